// Round 16
// baseline (812.038 us; speedup 1.0000x reference)
//
#include <hip/hip_runtime.h>

// B=2048 rows, T=2048 steps, H=32. Wave = ONE batch row; lane = (k, gp).
// gp0 owns gates {i,f}, gp1 owns {g,o}, each a full 32-wide fp32 dot -> no
// cross-lane reduce. R16 = R15 with the compile fix: weights held as
// ext_vector v4f (asm "+v" launder requires ext-vector/scalar, not the
// float4 struct). All f16 machinery deleted (builtin fdot2 absent -> scalar
// fallback tax; native v_dot2_f32_f16 fails numerics at 2.2e-2). Residency
// via R12-proven combo: waves_per_eu(2,2) + launder. h round-trip: per-wave
// fp32 LDS line (1 ds_write + 8 broadcast ds_read_b128 per step,
// wave-internal, no barriers). Split activations + permlane32_swap exchange
// + paired stores: R8-verified verbatim.

#define Bsz 2048
#define Tsz 2048
#define Hsz 32

typedef float v4f __attribute__((ext_vector_type(4)));

__device__ __forceinline__ float fast_rcp(float x) { return __builtin_amdgcn_rcpf(x); }
__device__ __forceinline__ float fast_exp2(float x) { return __builtin_amdgcn_exp2f(x); }

// xor-32 exchange; r0 = low-half-origin value (all lanes), r1 = high-half.
__device__ __forceinline__ void plswap(float a, float b, float& r0, float& r1) {
#if __has_builtin(__builtin_amdgcn_permlane32_swap)
    auto r = __builtin_amdgcn_permlane32_swap(__float_as_uint(a), __float_as_uint(b),
                                              false, false);
    r0 = __uint_as_float(r[0]);
    r1 = __uint_as_float(r[1]);
#else
    const bool hi = (threadIdx.x & 32) != 0;
    r0 = hi ? __shfl_xor(b, 32) : a;
    r1 = hi ? b : __shfl_xor(a, 32);
#endif
}

// 4-term fp32 dot into acc (4-deep fma chain)
#define DOT4(acc, W, H)                                                       \
    acc = __fmaf_rn((W).x, (H).x,                                             \
          __fmaf_rn((W).y, (H).y,                                             \
          __fmaf_rn((W).z, (H).z,                                             \
          __fmaf_rn((W).w, (H).w, (acc)))))

__global__ __launch_bounds__(256)
__attribute__((amdgpu_waves_per_eu(2, 2)))
void lstm_fwd_kernel(
    const float* __restrict__ x,      // (B, T)
    const float* __restrict__ w_ih,   // (4H, 1)
    const float* __restrict__ w_hh,   // (4H, H)
    const float* __restrict__ b_ih,   // (4H,)
    const float* __restrict__ b_hh,   // (4H,)
    float* __restrict__ out)          // (B, T*H)
{
    __shared__ float hbuf[4][32];     // one 128B fp32 h-line per wave(row)

    const int lane = threadIdx.x & 63;
    const int k    = lane & 31;
    const int gp   = lane >> 5;       // 0: gates {i,f} ; 1: gates {g,o}
    const int wv   = threadIdx.x >> 6;
    const int b    = blockIdx.x * 4 + wv;

    // ---- fp32 weights: rows jA = 64*gp + k (i|g), jB = jA + 32 (f|o);
    //      16 coalesced 16B loads = 64 VGPRs, laundered resident ----
    const int jA = gp * 64 + k, jB = jA + 32;
    v4f WA4[8], WB4[8];
    {
        const v4f* rA = reinterpret_cast<const v4f*>(w_hh + (size_t)jA * Hsz);
        const v4f* rB = reinterpret_cast<const v4f*>(w_hh + (size_t)jB * Hsz);
#pragma unroll
        for (int q = 0; q < 8; ++q) { WA4[q] = rA[q]; WB4[q] = rB[q]; }
    }
    asm volatile("" : "+v"(WA4[0]), "+v"(WA4[1]), "+v"(WA4[2]), "+v"(WA4[3]));
    asm volatile("" : "+v"(WA4[4]), "+v"(WA4[5]), "+v"(WA4[6]), "+v"(WA4[7]));
    asm volatile("" : "+v"(WB4[0]), "+v"(WB4[1]), "+v"(WB4[2]), "+v"(WB4[3]));
    asm volatile("" : "+v"(WB4[4]), "+v"(WB4[5]), "+v"(WB4[6]), "+v"(WB4[7]));

    const float wiA = w_ih[jA], bsA = b_ih[jA] + b_hh[jA];
    const float wiB = w_ih[jB], bsB = b_ih[jB] + b_hh[jB];

    // unified activation: a1 = A1*rcp(1+exp2(B1*p)) + C1
    // gp0 -> sigmoid(i), gp1 -> tanh(g); second value always sigmoid
    const float B1 = gp ? -2.885390082f : -1.442695041f;
    const float A1 = gp ? 2.0f : 1.0f;
    const float C1 = gp ? -1.0f : 0.0f;

    float c = 0.0f, h = 0.0f, hprev = 0.0f;
    hbuf[wv][k] = 0.0f;               // both halves, same addr/value: benign

    const float4* xq = reinterpret_cast<const float4*>(x + (size_t)b * Tsz);
    float* op = out + (size_t)b * (size_t)(Tsz * Hsz) + gp * 32 + k;
    const v4f* hr = reinterpret_cast<const v4f*>(&hbuf[wv][0]);

    float4 xc4 = xq[0];
#pragma unroll 1
    for (int t4 = 0; t4 < Tsz / 4; ++t4) {
        int nn = t4 + 1;
        if (nn > Tsz / 4 - 1) nn = Tsz / 4 - 1;   // clamped (dead last iter)
        float4 xn4 = xq[nn];
        const float xts[4] = {xc4.x, xc4.y, xc4.z, xc4.w};

#pragma unroll
        for (int u = 0; u < 4; ++u) {
            // previous h: 32 fp32 as 8 broadcast ds_read_b128
            v4f h0 = hr[0], h1 = hr[1], h2 = hr[2], h3 = hr[3];
            v4f h4 = hr[4], h5 = hr[5], h6 = hr[6], h7 = hr[7];

            // 8 independent 8-deep fma chains (4 per owned gate)
            float sA0 = 0.f, sA1 = 0.f, sA2 = 0.f, sA3 = 0.f;
            float sB0 = 0.f, sB1 = 0.f, sB2 = 0.f, sB3 = 0.f;
            DOT4(sA0, WA4[0], h0); DOT4(sB0, WB4[0], h0);
            DOT4(sA1, WA4[1], h1); DOT4(sB1, WB4[1], h1);
            DOT4(sA2, WA4[2], h2); DOT4(sB2, WB4[2], h2);
            DOT4(sA3, WA4[3], h3); DOT4(sB3, WB4[3], h3);
            DOT4(sA0, WA4[4], h4); DOT4(sB0, WB4[4], h4);
            DOT4(sA1, WA4[5], h5); DOT4(sB1, WB4[5], h5);
            DOT4(sA2, WA4[6], h6); DOT4(sB2, WB4[6], h6);
            DOT4(sA3, WA4[7], h7); DOT4(sB3, WB4[7], h7);

            const float xt = xts[u];
            const float pA = ((sA0 + sA1) + (sA2 + sA3)) + __fmaf_rn(wiA, xt, bsA);
            const float pB = ((sB0 + sB1) + (sB2 + sB3)) + __fmaf_rn(wiB, xt, bsB);

            // own-pair activations (R8-verified)
            const float a1 = __fmaf_rn(A1, fast_rcp(1.0f + fast_exp2(B1 * pA)), C1);
            const float a2 = fast_rcp(1.0f + fast_exp2(-1.442695041f * pB));

            float i_, g_, f_, o_;
            plswap(a1, a1, i_, g_);   // i_ = sig(i), g_ = tanh(g), all lanes
            plswap(a2, a2, f_, o_);   // f_ = sig(f), o_ = sig(o), all lanes

            c = __fmaf_rn(f_, c, i_ * g_);
            const float th =
                __fmaf_rn(2.0f, fast_rcp(1.0f + fast_exp2(-2.885390082f * c)), -1.0f);
            h = o_ * th;

            hbuf[wv][k] = h;          // next step's input (wave-internal)

            if (u & 1) {              // paired store: rows t-1 (gp0), t (gp1)
                *op = gp ? h : hprev;
                op += 64;
            } else {
                hprev = h;
            }
        }
        xc4 = xn4;
    }
}

extern "C" void kernel_launch(void* const* d_in, const int* in_sizes, int n_in,
                              void* d_out, int out_size, void* d_ws, size_t ws_size,
                              hipStream_t stream) {
    const float* x    = (const float*)d_in[0];
    const float* w_ih = (const float*)d_in[1];
    const float* w_hh = (const float*)d_in[2];
    const float* b_ih = (const float*)d_in[3];
    const float* b_hh = (const float*)d_in[4];
    float* out = (float*)d_out;

    dim3 grid(Bsz / 4);   // 512 blocks = 2 per CU -> 2 waves/SIMD
    dim3 block(256);      // 4 waves, each = one batch row (32 k x 2 gate-pairs)
    lstm_fwd_kernel<<<grid, block, 0, stream>>>(x, w_ih, w_hh, b_ih, b_hh, out);
}